// Round 5
// baseline (843.493 us; speedup 1.0000x reference)
//
#include <hip/hip_runtime.h>
#include <cstdint>

#define KNN 20
#define BV 8
#define NV 1024

// ---------- transpose x [B,N,3] -> hx [B,3,N]
__global__ __launch_bounds__(256) void k_transpose(const float* __restrict__ x, float* __restrict__ hx) {
    int id = blockIdx.x * 256 + threadIdx.x;
    if (id >= BV * 3 * NV) return;
    int n = id % NV;
    int c = (id / NV) % 3;
    int b = id / (3 * NV);
    hx[id] = x[(b * NV + n) * 3 + c];
}

// ---------- xx[b][n] = sum_c h[b][c][n]^2
__global__ __launch_bounds__(256) void k_xx(const float* __restrict__ h, float* __restrict__ xx,
                                            int C, int bstride) {
    int id = blockIdx.x * 256 + threadIdx.x;
    int n = id % NV, b = id / NV;
    if (b >= BV) return;
    const float* hp = h + (size_t)b * bstride + n;
    float s = 0.f;
    for (int c = 0; c < C; ++c) { float v = hp[(size_t)c * NV]; s += v * v; }
    xx[b * NV + n] = s;
}

// ---------- FUSED kNN: neg-sqdist rows in registers, top-20 in-wave, no D matrix.
// grid (B, N/32); block 512 = 8 waves; wave w owns rows i0+4w..+3; lane owns 16 j's.
__global__ __launch_bounds__(512) void k_knn(const float* __restrict__ h, const float* __restrict__ xx,
                                             int C, int bstride, int* __restrict__ idx) {
    __shared__ float Bs[8][1024];
    const int b = blockIdx.x, i0 = blockIdx.y * 32;
    const int t = threadIdx.x, lane = t & 63, w = t >> 6;
    const int irow = i0 + w * 4;
    float acc[4][16] = {};
    const float* hb = h + (size_t)b * bstride;

    for (int c0 = 0; c0 < C; c0 += 8) {
        __syncthreads();
#pragma unroll
        for (int r = 0; r < 4; ++r) {              // stage Bs[8][1024] = h[c0..c0+7][:]
            int e = r * 512 + t;                   // 2048 float4 groups
            int cc = e >> 8, jj = e & 255;
            float4 v = make_float4(0.f, 0.f, 0.f, 0.f);
            if (c0 + cc < C) v = *(const float4*)&hb[(size_t)(c0 + cc) * NV + jj * 4];
            *(float4*)&Bs[cc][jj * 4] = v;
        }
        __syncthreads();
#pragma unroll
        for (int c = 0; c < 8; ++c) {
            float4 arv = *(const float4*)&Bs[c][irow];     // wave-uniform broadcast
            float ar[4] = {arv.x, arv.y, arv.z, arv.w};
            float br[16];
#pragma unroll
            for (int g = 0; g < 4; ++g) {
                float4 bv = *(const float4*)&Bs[c][g * 256 + (lane << 2)];  // conflict-free b128
                br[g * 4 + 0] = bv.x; br[g * 4 + 1] = bv.y;
                br[g * 4 + 2] = bv.z; br[g * 4 + 3] = bv.w;
            }
#pragma unroll
            for (int a = 0; a < 4; ++a)
#pragma unroll
                for (int q = 0; q < 16; ++q) acc[a][q] += ar[a] * br[q];
        }
    }

    // neg sqdist = 2*dot - xx_i - xx_j
    const float* xb = xx + b * NV;
    float xxj[16];
#pragma unroll
    for (int g = 0; g < 4; ++g) {
        float4 xv = *(const float4*)&xb[g * 256 + (lane << 2)];
        xxj[g * 4 + 0] = xv.x; xxj[g * 4 + 1] = xv.y;
        xxj[g * 4 + 2] = xv.z; xxj[g * 4 + 3] = xv.w;
    }
#pragma unroll
    for (int a = 0; a < 4; ++a) {
        float xi = xb[irow + a];
#pragma unroll
        for (int q = 0; q < 16; ++q) acc[a][q] = 2.f * acc[a][q] - xi - xxj[q];
    }

    // ---- wave-parallel top-20, 4 rows' chains INTERLEAVED for ILP
    int* opb = idx + ((size_t)(b * NV + irow)) * KNN;   // rows contiguous: [a*KNN + s]
#pragma unroll 1
    for (int s = 0; s < KNN; ++s) {
        unsigned gsu[4], mysu[4]; int myj[4];
#pragma unroll
        for (int a = 0; a < 4; ++a) {
            float bv = acc[a][0]; int bq = 0;
#pragma unroll
            for (int q = 1; q < 16; ++q)            // static idx; strict > keeps lower q (= lower j)
                if (acc[a][q] > bv) { bv = acc[a][q]; bq = q; }
            unsigned u = __float_as_uint(bv);
            unsigned su = ((int)u < 0) ? ~u : (u | 0x80000000u);   // sortable uint
            mysu[a] = su; gsu[a] = su;
            myj[a] = ((bq >> 2) << 8) | (lane << 2) | (bq & 3);
        }
#pragma unroll
        for (int off = 1; off < 64; off <<= 1) {    // 4 interleaved value-butterflies
#pragma unroll
            for (int a = 0; a < 4; ++a) {
                unsigned o = __shfl_xor(gsu[a], off, 64);
                gsu[a] = (o > gsu[a]) ? o : gsu[a];
            }
        }
#pragma unroll
        for (int a = 0; a < 4; ++a) {
            unsigned long long m = __ballot(mysu[a] == gsu[a]);
            int j;
            if (m & (m - 1)) {                      // rare value tie across lanes: lowest j wins
                int nj = (mysu[a] == gsu[a]) ? (1023 - myj[a]) : -1;
#pragma unroll
                for (int off = 1; off < 64; off <<= 1) {
                    int o = __shfl_xor(nj, off, 64);
                    nj = (o > nj) ? o : nj;
                }
                j = 1023 - nj;
            } else {                                // unique winner: broadcast its j
                int wl = (int)__ffsll(m) - 1;
                j = __builtin_amdgcn_readlane(myj[a], wl);
            }
            if (lane == 0) opb[a * KNN + s] = j;
            // winner lane poisons its extracted slot (static-index cndmask chain)
            int wq = (((j >> 2) & 63) == lane) ? (((j >> 8) << 2) | (j & 3)) : 99;
#pragma unroll
            for (int q = 0; q < 16; ++q)
                if (wq == q) acc[a][q] = -3.4e38f;
        }
    }
}

// ---------- pack A = [ Wl ; Wr - Wl ]  (2O x C)
__global__ __launch_bounds__(256) void k_pack(const float* __restrict__ W, float* __restrict__ wb,
                                              int C, int O) {
    int id = blockIdx.x * 256 + threadIdx.x;
    if (id >= 2 * O * C) return;
    int c = id % C, o = (id / C) % O, half = id / (C * O);
    float wl = W[(size_t)o * 2 * C + c];
    wb[id] = half ? (W[(size_t)o * 2 * C + C + c] - wl) : wl;
}

// ---------- out[b][o][n] = sum_c A[o][c] * h[b][c][n]   (64x128 tile, 4x8 micro)
__global__ __launch_bounds__(256) void k_gemm(const float* __restrict__ A, int astride,
                                              const float* __restrict__ h, int bstride, int C,
                                              float* __restrict__ out, int O) {
    __shared__ float Ws[8][64], Hs[8][128];
    const int b = blockIdx.z, o0 = blockIdx.y * 64, n0 = blockIdx.x * 128;
    const int t = threadIdx.x, tx = t & 15, ty = t >> 4;
    float acc[4][8] = {};
    const float* hb = h + (size_t)b * bstride;
    for (int c0 = 0; c0 < C; c0 += 8) {
#pragma unroll
        for (int q = 0; q < 2; ++q) {
            int e = t + q * 256;
            int oo = e >> 3, cc = e & 7;
            Ws[cc][oo] = ((c0 + cc) < C) ? A[(size_t)(o0 + oo) * astride + c0 + cc] : 0.f;
        }
        {
            int cc = t >> 5, nn4 = t & 31;
            float4 v = make_float4(0.f, 0.f, 0.f, 0.f);
            if (c0 + cc < C) v = *(const float4*)&hb[(size_t)(c0 + cc) * NV + n0 + nn4 * 4];
            *(float4*)&Hs[cc][nn4 * 4] = v;
        }
        __syncthreads();
#pragma unroll
        for (int c = 0; c < 8; ++c) {
            float4 wv = *(const float4*)&Ws[c][ty * 4];
            float ar[4] = {wv.x, wv.y, wv.z, wv.w};
            float br[8];
            float4 h0 = *(const float4*)&Hs[c][tx * 4];
            float4 h1 = *(const float4*)&Hs[c][64 + tx * 4];
            br[0] = h0.x; br[1] = h0.y; br[2] = h0.z; br[3] = h0.w;
            br[4] = h1.x; br[5] = h1.y; br[6] = h1.z; br[7] = h1.w;
#pragma unroll
            for (int a = 0; a < 4; ++a)
#pragma unroll
                for (int q = 0; q < 8; ++q) acc[a][q] += ar[a] * br[q];
        }
        __syncthreads();
    }
#pragma unroll
    for (int a = 0; a < 4; ++a) {
        int o = o0 + ty * 4 + a;
        float* outp = out + ((size_t)b * O + o) * NV + n0;
        float4 s0 = make_float4(acc[a][0], acc[a][1], acc[a][2], acc[a][3]);
        float4 s1 = make_float4(acc[a][4], acc[a][5], acc[a][6], acc[a][7]);
        *(float4*)&outp[tx * 4] = s0;
        *(float4*)&outp[64 + tx * 4] = s1;
    }
}

// ---------- h_out[b][o][n] = mean_k lrelu( a*(p[b][o][idx[n][k]] + d[b][o][n]) + c0 )
__global__ __launch_bounds__(256) void k_edge(const float* __restrict__ pd,
                                              const int* __restrict__ idx,
                                              const float* __restrict__ ga, const float* __restrict__ be,
                                              const float* __restrict__ mu, const float* __restrict__ va,
                                              float* __restrict__ out, int out_bstride, int O) {
    const int n = blockIdx.x * 256 + threadIdx.x;
    const int o = blockIdx.y, b = blockIdx.z;
    const float a  = ga[o] / sqrtf(va[o] + 1e-5f);
    const float c0 = be[o] - mu[o] * a;
    const float* pb = pd + ((size_t)b * 2 * O + o) * NV;
    const float dv  = pd[((size_t)b * 2 * O + O + o) * NV + n];
    const int* ip   = idx + ((size_t)b * NV + n) * KNN;
    float s = 0.f;
#pragma unroll
    for (int k = 0; k < KNN; ++k) {
        int j = ip[k];
        float y = fmaf(a, pb[j] + dv, c0);
        s += (y > 0.f) ? y : 0.2f * y;
    }
    out[(size_t)b * out_bstride + (size_t)o * NV + n] = s * (1.f / KNN);
}

// ---------- pooled[b][o] = mean_n hf[b][o][n]
__global__ __launch_bounds__(256) void k_pool(const float* __restrict__ hf, float* __restrict__ pooled) {
    const int o = blockIdx.x, b = blockIdx.y;
    const float* hp = hf + ((size_t)b * 512 + o) * NV;
    float s = 0.f;
    for (int i = threadIdx.x; i < NV; i += 256) s += hp[i];
#pragma unroll
    for (int off = 32; off > 0; off >>= 1) s += __shfl_down(s, off, 64);
    __shared__ float red[4];
    if ((threadIdx.x & 63) == 0) red[threadIdx.x >> 6] = s;
    __syncthreads();
    if (threadIdx.x == 0)
        pooled[(size_t)b * 512 + o] = (red[0] + red[1] + red[2] + red[3]) * (1.f / NV);
}

// ---------- out[b][j] = sum_o pooled[b][o] * We[j][o]
__global__ __launch_bounds__(256) void k_final(const float* __restrict__ pooled, const float* __restrict__ We,
                                               float* __restrict__ out) {
    const int j = threadIdx.x, b = blockIdx.x;
    __shared__ float ps[512];
    for (int o = threadIdx.x; o < 512; o += 256) ps[o] = pooled[b * 512 + o];
    __syncthreads();
    float s = 0.f;
    for (int o = 0; o < 512; ++o) s += ps[o] * We[(size_t)j * 512 + o];
    out[b * 256 + j] = s;
}

extern "C" void kernel_launch(void* const* d_in, const int* in_sizes, int n_in,
                              void* d_out, int out_size, void* d_ws, size_t ws_size,
                              hipStream_t stream) {
    const float* x  = (const float*)d_in[0];
    const float* W0 = (const float*)d_in[1];
    const float* g0 = (const float*)d_in[2];
    const float* b0 = (const float*)d_in[3];
    const float* m0 = (const float*)d_in[4];
    const float* v0 = (const float*)d_in[5];
    const float* W1 = (const float*)d_in[6];
    const float* g1 = (const float*)d_in[7];
    const float* b1 = (const float*)d_in[8];
    const float* m1 = (const float*)d_in[9];
    const float* v1 = (const float*)d_in[10];
    const float* W2 = (const float*)d_in[11];
    const float* g2 = (const float*)d_in[12];
    const float* b2 = (const float*)d_in[13];
    const float* m2 = (const float*)d_in[14];
    const float* v2 = (const float*)d_in[15];
    const float* Wf = (const float*)d_in[16];
    const float* gf = (const float*)d_in[17];
    const float* bf = (const float*)d_in[18];
    const float* mf = (const float*)d_in[19];
    const float* vf = (const float*)d_in[20];
    const float* We = (const float*)d_in[21];

    float* ws = (float*)d_ws;
    float* hx     = ws;                         // 24576
    float* cat    = hx + 24576;                 // 3670016
    float* xx     = cat + 3670016;              // 8192
    int*   idx    = (int*)(xx + 8192);          // 163840 ints
    float* pd     = (float*)(idx + 163840);     // 8388608 (2O max = 1024)
    float* wb     = pd + 8388608;               // 458752
    float* hf     = wb + 458752;                // 4194304
    float* pooled = hf + 4194304;               // 4096

    k_transpose<<<96, 256, 0, stream>>>(x, hx);

    auto run_layer = [&](const float* h, int C, int bstride, const float* W,
                         const float* g, const float* be, const float* m, const float* v,
                         int O, float* outp, int obstride) {
        k_xx<<<32, 256, 0, stream>>>(h, xx, C, bstride);
        k_knn<<<dim3(8, 32), 512, 0, stream>>>(h, xx, C, bstride, idx);
        int pn = 2 * O * C;
        k_pack<<<(pn + 255) / 256, 256, 0, stream>>>(W, wb, C, O);
        k_gemm<<<dim3(8, 2 * O / 64, 8), 256, 0, stream>>>(wb, C, h, bstride, C, pd, 2 * O);
        k_edge<<<dim3(4, O, 8), 256, 0, stream>>>(pd, idx, g, be, m, v, outp, obstride, O);
    };

    run_layer(hx, 3, 3 * NV, W0, g0, b0, m0, v0, 64, cat, 448 * NV);
    run_layer(cat, 64, 448 * NV, W1, g1, b1, m1, v1, 128, cat + 64 * NV, 448 * NV);
    run_layer(cat + 64 * NV, 128, 448 * NV, W2, g2, b2, m2, v2, 256, cat + 192 * NV, 448 * NV);
    run_layer(cat, 448, 448 * NV, Wf, gf, bf, mf, vf, 512, hf, 512 * NV);

    k_pool<<<dim3(512, 8), 256, 0, stream>>>(hf, pooled);
    k_final<<<8, 256, 0, stream>>>(pooled, We, (float*)d_out);
}

// Round 6
// 843.335 us; speedup vs baseline: 1.0002x; 1.0002x over previous
//
#include <hip/hip_runtime.h>
#include <cstdint>

#define KNN 20
#define BV 8
#define NV 1024

// ---------- transpose x [B,N,3] -> hx [B,3,N]
__global__ __launch_bounds__(256) void k_transpose(const float* __restrict__ x, float* __restrict__ hx) {
    int id = blockIdx.x * 256 + threadIdx.x;
    if (id >= BV * 3 * NV) return;
    int n = id % NV;
    int c = (id / NV) % 3;
    int b = id / (3 * NV);
    hx[id] = x[(b * NV + n) * 3 + c];
}

// ---------- xx[b][n] = sum_c h[b][c][n]^2
__global__ __launch_bounds__(256) void k_xx(const float* __restrict__ h, float* __restrict__ xx,
                                            int C, int bstride) {
    int id = blockIdx.x * 256 + threadIdx.x;
    int n = id % NV, b = id / NV;
    if (b >= BV) return;
    const float* hp = h + (size_t)b * bstride + n;
    float s = 0.f;
    for (int c = 0; c < C; ++c) { float v = hp[(size_t)c * NV]; s += v * v; }
    xx[b * NV + n] = s;
}

// ---------- FUSED kNN: neg-sqdist rows in registers, top-20 in-wave, no D matrix.
// grid (B, N/32); block 512 = 8 waves; wave w owns rows i0+4w..+3; lane owns 16 j's.
__global__ __launch_bounds__(512) void k_knn(const float* __restrict__ h, const float* __restrict__ xx,
                                             int C, int bstride, int* __restrict__ idx) {
    __shared__ float Bs[8][1024];
    const int b = blockIdx.x, i0 = blockIdx.y * 32;
    const int t = threadIdx.x, lane = t & 63, w = t >> 6;
    const int irow = i0 + w * 4;
    float acc[4][16] = {};
    const float* hb = h + (size_t)b * bstride;

    for (int c0 = 0; c0 < C; c0 += 8) {
        __syncthreads();
#pragma unroll
        for (int r = 0; r < 4; ++r) {              // stage Bs[8][1024] = h[c0..c0+7][:]
            int e = r * 512 + t;                   // 2048 float4 groups
            int cc = e >> 8, jj = e & 255;
            float4 v = make_float4(0.f, 0.f, 0.f, 0.f);
            if (c0 + cc < C) v = *(const float4*)&hb[(size_t)(c0 + cc) * NV + jj * 4];
            *(float4*)&Bs[cc][jj * 4] = v;
        }
        __syncthreads();
#pragma unroll
        for (int c = 0; c < 8; ++c) {
            float4 arv = *(const float4*)&Bs[c][irow];     // wave-uniform broadcast
            float ar[4] = {arv.x, arv.y, arv.z, arv.w};
            float br[16];
#pragma unroll
            for (int g = 0; g < 4; ++g) {
                float4 bv = *(const float4*)&Bs[c][g * 256 + (lane << 2)];  // conflict-free b128
                br[g * 4 + 0] = bv.x; br[g * 4 + 1] = bv.y;
                br[g * 4 + 2] = bv.z; br[g * 4 + 3] = bv.w;
            }
#pragma unroll
            for (int a = 0; a < 4; ++a)
#pragma unroll
                for (int q = 0; q < 16; ++q) acc[a][q] += ar[a] * br[q];
        }
    }

    // neg sqdist = 2*dot - xx_i - xx_j
    const float* xb = xx + b * NV;
    float xxj[16];
#pragma unroll
    for (int g = 0; g < 4; ++g) {
        float4 xv = *(const float4*)&xb[g * 256 + (lane << 2)];
        xxj[g * 4 + 0] = xv.x; xxj[g * 4 + 1] = xv.y;
        xxj[g * 4 + 2] = xv.z; xxj[g * 4 + 3] = xv.w;
    }
#pragma unroll
    for (int a = 0; a < 4; ++a) {
        float xi = xb[irow + a];
#pragma unroll
        for (int q = 0; q < 16; ++q) acc[a][q] = 2.f * acc[a][q] - xi - xxj[q];
    }

    // ---- wave-parallel top-20, 4 rows' chains INTERLEAVED for ILP
    int* opb = idx + ((size_t)(b * NV + irow)) * KNN;   // rows contiguous: [a*KNN + s]
#pragma unroll 1
    for (int s = 0; s < KNN; ++s) {
        unsigned gsu[4], mysu[4]; int myj[4];
#pragma unroll
        for (int a = 0; a < 4; ++a) {
            float bv = acc[a][0]; int bq = 0;
#pragma unroll
            for (int q = 1; q < 16; ++q)            // static idx; strict > keeps lower q (= lower j)
                if (acc[a][q] > bv) { bv = acc[a][q]; bq = q; }
            unsigned u = __float_as_uint(bv);
            unsigned su = ((int)u < 0) ? ~u : (u | 0x80000000u);   // sortable uint
            mysu[a] = su; gsu[a] = su;
            myj[a] = ((bq >> 2) << 8) | (lane << 2) | (bq & 3);
        }
#pragma unroll
        for (int off = 1; off < 64; off <<= 1) {    // 4 interleaved value-butterflies
#pragma unroll
            for (int a = 0; a < 4; ++a) {
                unsigned o = __shfl_xor(gsu[a], off, 64);
                gsu[a] = (o > gsu[a]) ? o : gsu[a];
            }
        }
#pragma unroll
        for (int a = 0; a < 4; ++a) {
            unsigned long long m = __ballot(mysu[a] == gsu[a]);
            int j;
            if (m & (m - 1)) {                      // rare value tie across lanes: lowest j wins
                int nj = (mysu[a] == gsu[a]) ? (1023 - myj[a]) : -1;
#pragma unroll
                for (int off = 1; off < 64; off <<= 1) {
                    int o = __shfl_xor(nj, off, 64);
                    nj = (o > nj) ? o : nj;
                }
                j = 1023 - nj;
            } else {                                // unique winner: broadcast its j
                int wl = (int)__ffsll(m) - 1;
                j = __builtin_amdgcn_readlane(myj[a], wl);
            }
            if (lane == 0) opb[a * KNN + s] = j;
            // winner lane poisons its extracted slot (static-index cndmask chain)
            int wq = (((j >> 2) & 63) == lane) ? (((j >> 8) << 2) | (j & 3)) : 99;
#pragma unroll
            for (int q = 0; q < 16; ++q)
                if (wq == q) acc[a][q] = -3.4e38f;
        }
    }
}

// ---------- pack A = [ Wl ; Wr - Wl ]  (2O x C)
__global__ __launch_bounds__(256) void k_pack(const float* __restrict__ W, float* __restrict__ wb,
                                              int C, int O) {
    int id = blockIdx.x * 256 + threadIdx.x;
    if (id >= 2 * O * C) return;
    int c = id % C, o = (id / C) % O, half = id / (C * O);
    float wl = W[(size_t)o * 2 * C + c];
    wb[id] = half ? (W[(size_t)o * 2 * C + C + c] - wl) : wl;
}

// ---------- out[b][o][n] = sum_c A[o][c] * h[b][c][n]   (64x128 tile, 4x8 micro)
__global__ __launch_bounds__(256) void k_gemm(const float* __restrict__ A, int astride,
                                              const float* __restrict__ h, int bstride, int C,
                                              float* __restrict__ out, int O) {
    __shared__ float Ws[8][64], Hs[8][128];
    const int b = blockIdx.z, o0 = blockIdx.y * 64, n0 = blockIdx.x * 128;
    const int t = threadIdx.x, tx = t & 15, ty = t >> 4;
    float acc[4][8] = {};
    const float* hb = h + (size_t)b * bstride;
    for (int c0 = 0; c0 < C; c0 += 8) {
#pragma unroll
        for (int q = 0; q < 2; ++q) {
            int e = t + q * 256;
            int oo = e >> 3, cc = e & 7;
            Ws[cc][oo] = ((c0 + cc) < C) ? A[(size_t)(o0 + oo) * astride + c0 + cc] : 0.f;
        }
        {
            int cc = t >> 5, nn4 = t & 31;
            float4 v = make_float4(0.f, 0.f, 0.f, 0.f);
            if (c0 + cc < C) v = *(const float4*)&hb[(size_t)(c0 + cc) * NV + n0 + nn4 * 4];
            *(float4*)&Hs[cc][nn4 * 4] = v;
        }
        __syncthreads();
#pragma unroll
        for (int c = 0; c < 8; ++c) {
            float4 wv = *(const float4*)&Ws[c][ty * 4];
            float ar[4] = {wv.x, wv.y, wv.z, wv.w};
            float br[8];
            float4 h0 = *(const float4*)&Hs[c][tx * 4];
            float4 h1 = *(const float4*)&Hs[c][64 + tx * 4];
            br[0] = h0.x; br[1] = h0.y; br[2] = h0.z; br[3] = h0.w;
            br[4] = h1.x; br[5] = h1.y; br[6] = h1.z; br[7] = h1.w;
#pragma unroll
            for (int a = 0; a < 4; ++a)
#pragma unroll
                for (int q = 0; q < 8; ++q) acc[a][q] += ar[a] * br[q];
        }
        __syncthreads();
    }
#pragma unroll
    for (int a = 0; a < 4; ++a) {
        int o = o0 + ty * 4 + a;
        float* outp = out + ((size_t)b * O + o) * NV + n0;
        float4 s0 = make_float4(acc[a][0], acc[a][1], acc[a][2], acc[a][3]);
        float4 s1 = make_float4(acc[a][4], acc[a][5], acc[a][6], acc[a][7]);
        *(float4*)&outp[tx * 4] = s0;
        *(float4*)&outp[64 + tx * 4] = s1;
    }
}

// ---------- h_out[b][o][n] = mean_k lrelu( a*(p[b][o][idx[n][k]] + d[b][o][n]) + c0 )
__global__ __launch_bounds__(256) void k_edge(const float* __restrict__ pd,
                                              const int* __restrict__ idx,
                                              const float* __restrict__ ga, const float* __restrict__ be,
                                              const float* __restrict__ mu, const float* __restrict__ va,
                                              float* __restrict__ out, int out_bstride, int O) {
    const int n = blockIdx.x * 256 + threadIdx.x;
    const int o = blockIdx.y, b = blockIdx.z;
    const float a  = ga[o] / sqrtf(va[o] + 1e-5f);
    const float c0 = be[o] - mu[o] * a;
    const float* pb = pd + ((size_t)b * 2 * O + o) * NV;
    const float dv  = pd[((size_t)b * 2 * O + O + o) * NV + n];
    const int* ip   = idx + ((size_t)b * NV + n) * KNN;
    float s = 0.f;
#pragma unroll
    for (int k = 0; k < KNN; ++k) {
        int j = ip[k];
        float y = fmaf(a, pb[j] + dv, c0);
        s += (y > 0.f) ? y : 0.2f * y;
    }
    out[(size_t)b * out_bstride + (size_t)o * NV + n] = s * (1.f / KNN);
}

// ---------- pooled[b][o] = mean_n hf[b][o][n]
__global__ __launch_bounds__(256) void k_pool(const float* __restrict__ hf, float* __restrict__ pooled) {
    const int o = blockIdx.x, b = blockIdx.y;
    const float* hp = hf + ((size_t)b * 512 + o) * NV;
    float s = 0.f;
    for (int i = threadIdx.x; i < NV; i += 256) s += hp[i];
#pragma unroll
    for (int off = 32; off > 0; off >>= 1) s += __shfl_down(s, off, 64);
    __shared__ float red[4];
    if ((threadIdx.x & 63) == 0) red[threadIdx.x >> 6] = s;
    __syncthreads();
    if (threadIdx.x == 0)
        pooled[(size_t)b * 512 + o] = (red[0] + red[1] + red[2] + red[3]) * (1.f / NV);
}

// ---------- out[b][j] = sum_o pooled[b][o] * We[j][o]
__global__ __launch_bounds__(256) void k_final(const float* __restrict__ pooled, const float* __restrict__ We,
                                               float* __restrict__ out) {
    const int j = threadIdx.x, b = blockIdx.x;
    __shared__ float ps[512];
    for (int o = threadIdx.x; o < 512; o += 256) ps[o] = pooled[b * 512 + o];
    __syncthreads();
    float s = 0.f;
    for (int o = 0; o < 512; ++o) s += ps[o] * We[(size_t)j * 512 + o];
    out[b * 256 + j] = s;
}

extern "C" void kernel_launch(void* const* d_in, const int* in_sizes, int n_in,
                              void* d_out, int out_size, void* d_ws, size_t ws_size,
                              hipStream_t stream) {
    const float* x  = (const float*)d_in[0];
    const float* W0 = (const float*)d_in[1];
    const float* g0 = (const float*)d_in[2];
    const float* b0 = (const float*)d_in[3];
    const float* m0 = (const float*)d_in[4];
    const float* v0 = (const float*)d_in[5];
    const float* W1 = (const float*)d_in[6];
    const float* g1 = (const float*)d_in[7];
    const float* b1 = (const float*)d_in[8];
    const float* m1 = (const float*)d_in[9];
    const float* v1 = (const float*)d_in[10];
    const float* W2 = (const float*)d_in[11];
    const float* g2 = (const float*)d_in[12];
    const float* b2 = (const float*)d_in[13];
    const float* m2 = (const float*)d_in[14];
    const float* v2 = (const float*)d_in[15];
    const float* Wf = (const float*)d_in[16];
    const float* gf = (const float*)d_in[17];
    const float* bf = (const float*)d_in[18];
    const float* mf = (const float*)d_in[19];
    const float* vf = (const float*)d_in[20];
    const float* We = (const float*)d_in[21];

    float* ws = (float*)d_ws;
    float* hx     = ws;                         // 24576
    float* cat    = hx + 24576;                 // 3670016
    float* xx     = cat + 3670016;              // 8192
    int*   idx    = (int*)(xx + 8192);          // 163840 ints
    float* pd     = (float*)(idx + 163840);     // 8388608 (2O max = 1024)
    float* wb     = pd + 8388608;               // 458752
    float* hf     = wb + 458752;                // 4194304
    float* pooled = hf + 4194304;               // 4096

    k_transpose<<<96, 256, 0, stream>>>(x, hx);

    auto run_layer = [&](const float* h, int C, int bstride, const float* W,
                         const float* g, const float* be, const float* m, const float* v,
                         int O, float* outp, int obstride) {
        k_xx<<<32, 256, 0, stream>>>(h, xx, C, bstride);
        k_knn<<<dim3(8, 32), 512, 0, stream>>>(h, xx, C, bstride, idx);
        int pn = 2 * O * C;
        k_pack<<<(pn + 255) / 256, 256, 0, stream>>>(W, wb, C, O);
        k_gemm<<<dim3(8, 2 * O / 64, 8), 256, 0, stream>>>(wb, C, h, bstride, C, pd, 2 * O);
        k_edge<<<dim3(4, O, 8), 256, 0, stream>>>(pd, idx, g, be, m, v, outp, obstride, O);
    };

    run_layer(hx, 3, 3 * NV, W0, g0, b0, m0, v0, 64, cat, 448 * NV);
    run_layer(cat, 64, 448 * NV, W1, g1, b1, m1, v1, 128, cat + 64 * NV, 448 * NV);
    run_layer(cat + 64 * NV, 128, 448 * NV, W2, g2, b2, m2, v2, 256, cat + 192 * NV, 448 * NV);
    run_layer(cat, 448, 448 * NV, Wf, gf, bf, mf, vf, 512, hf, 512 * NV);

    k_pool<<<dim3(512, 8), 256, 0, stream>>>(hf, pooled);
    k_final<<<8, 256, 0, stream>>>(pooled, We, (float*)d_out);
}

// Round 7
// 842.954 us; speedup vs baseline: 1.0006x; 1.0005x over previous
//
#include <hip/hip_runtime.h>
#include <cstdint>

#define KNN 20
#define BV 8
#define NV 1024

// ---------- transpose x [B,N,3] -> hx [B,3,N]
__global__ __launch_bounds__(256) void k_transpose(const float* __restrict__ x, float* __restrict__ hx) {
    int id = blockIdx.x * 256 + threadIdx.x;
    if (id >= BV * 3 * NV) return;
    int n = id % NV;
    int c = (id / NV) % 3;
    int b = id / (3 * NV);
    hx[id] = x[(b * NV + n) * 3 + c];
}

// ---------- xx[b][n] = sum_c h[b][c][n]^2
__global__ __launch_bounds__(256) void k_xx(const float* __restrict__ h, float* __restrict__ xx,
                                            int C, int bstride) {
    int id = blockIdx.x * 256 + threadIdx.x;
    int n = id % NV, b = id / NV;
    if (b >= BV) return;
    const float* hp = h + (size_t)b * bstride + n;
    float s = 0.f;
    for (int c = 0; c < C; ++c) { float v = hp[(size_t)c * NV]; s += v * v; }
    xx[b * NV + n] = s;
}

// ---------- FUSED kNN: neg-sqdist rows in registers, top-20 in-wave, no D matrix.
// grid (B, N/32); block 512 = 8 waves; wave w owns rows i0+4w..+3; lane owns 16 j's.
__global__ __launch_bounds__(512) void k_knn(const float* __restrict__ h, const float* __restrict__ xx,
                                             int C, int bstride, int* __restrict__ idx) {
    __shared__ float Bs[8][1024];
    const int b = blockIdx.x, i0 = blockIdx.y * 32;
    const int t = threadIdx.x, lane = t & 63, w = t >> 6;
    const int irow = i0 + w * 4;
    float acc[4][16] = {};
    const float* hb = h + (size_t)b * bstride;

    for (int c0 = 0; c0 < C; c0 += 8) {
        __syncthreads();
#pragma unroll
        for (int r = 0; r < 4; ++r) {              // stage Bs[8][1024] = h[c0..c0+7][:]
            int e = r * 512 + t;                   // 2048 float4 groups
            int cc = e >> 8, jj = e & 255;
            float4 v = make_float4(0.f, 0.f, 0.f, 0.f);
            if (c0 + cc < C) v = *(const float4*)&hb[(size_t)(c0 + cc) * NV + jj * 4];
            *(float4*)&Bs[cc][jj * 4] = v;
        }
        __syncthreads();
#pragma unroll
        for (int c = 0; c < 8; ++c) {
            float4 arv = *(const float4*)&Bs[c][irow];     // wave-uniform broadcast
            float ar[4] = {arv.x, arv.y, arv.z, arv.w};
            float br[16];
#pragma unroll
            for (int g = 0; g < 4; ++g) {
                float4 bv = *(const float4*)&Bs[c][g * 256 + (lane << 2)];  // conflict-free b128
                br[g * 4 + 0] = bv.x; br[g * 4 + 1] = bv.y;
                br[g * 4 + 2] = bv.z; br[g * 4 + 3] = bv.w;
            }
#pragma unroll
            for (int a = 0; a < 4; ++a)
#pragma unroll
                for (int q = 0; q < 16; ++q) acc[a][q] += ar[a] * br[q];
        }
    }

    // neg sqdist = 2*dot - xx_i - xx_j
    const float* xb = xx + b * NV;
    float xxj[16];
#pragma unroll
    for (int g = 0; g < 4; ++g) {
        float4 xv = *(const float4*)&xb[g * 256 + (lane << 2)];
        xxj[g * 4 + 0] = xv.x; xxj[g * 4 + 1] = xv.y;
        xxj[g * 4 + 2] = xv.z; xxj[g * 4 + 3] = xv.w;
    }
#pragma unroll
    for (int a = 0; a < 4; ++a) {
        float xi = xb[irow + a];
#pragma unroll
        for (int q = 0; q < 16; ++q) acc[a][q] = 2.f * acc[a][q] - xi - xxj[q];
    }

    // ---- wave-parallel top-20, 4 rows' chains INTERLEAVED for ILP
    int* opb = idx + ((size_t)(b * NV + irow)) * KNN;   // rows contiguous: [a*KNN + s]
#pragma unroll 1
    for (int s = 0; s < KNN; ++s) {
        unsigned gsu[4], mysu[4]; int myj[4];
#pragma unroll
        for (int a = 0; a < 4; ++a) {
            float bv = acc[a][0]; int bq = 0;
#pragma unroll
            for (int q = 1; q < 16; ++q)            // static idx; strict > keeps lower q (= lower j)
                if (acc[a][q] > bv) { bv = acc[a][q]; bq = q; }
            unsigned u = __float_as_uint(bv);
            unsigned su = ((int)u < 0) ? ~u : (u | 0x80000000u);   // sortable uint
            mysu[a] = su; gsu[a] = su;
            myj[a] = ((bq >> 2) << 8) | (lane << 2) | (bq & 3);
        }
#pragma unroll
        for (int off = 1; off < 64; off <<= 1) {    // 4 interleaved value-butterflies
#pragma unroll
            for (int a = 0; a < 4; ++a) {
                unsigned o = __shfl_xor(gsu[a], off, 64);
                gsu[a] = (o > gsu[a]) ? o : gsu[a];
            }
        }
#pragma unroll
        for (int a = 0; a < 4; ++a) {
            unsigned long long m = __ballot(mysu[a] == gsu[a]);
            int j;
            if (m & (m - 1)) {                      // rare value tie across lanes: lowest j wins
                int nj = (mysu[a] == gsu[a]) ? (1023 - myj[a]) : -1;
#pragma unroll
                for (int off = 1; off < 64; off <<= 1) {
                    int o = __shfl_xor(nj, off, 64);
                    nj = (o > nj) ? o : nj;
                }
                j = 1023 - nj;
            } else {                                // unique winner: broadcast its j
                int wl = (int)__ffsll(m) - 1;
                j = __builtin_amdgcn_readlane(myj[a], wl);
            }
            if (lane == 0) opb[a * KNN + s] = j;
            // winner lane poisons its extracted slot (static-index cndmask chain)
            int wq = (((j >> 2) & 63) == lane) ? (((j >> 8) << 2) | (j & 3)) : 99;
#pragma unroll
            for (int q = 0; q < 16; ++q)
                if (wq == q) acc[a][q] = -3.4e38f;
        }
    }
}

// ---------- pack A = [ Wl ; Wr - Wl ]  (2O x C)
__global__ __launch_bounds__(256) void k_pack(const float* __restrict__ W, float* __restrict__ wb,
                                              int C, int O) {
    int id = blockIdx.x * 256 + threadIdx.x;
    if (id >= 2 * O * C) return;
    int c = id % C, o = (id / C) % O, half = id / (C * O);
    float wl = W[(size_t)o * 2 * C + c];
    wb[id] = half ? (W[(size_t)o * 2 * C + C + c] - wl) : wl;
}

// ---------- out[b][o][n] = sum_c A[o][c] * h[b][c][n]   (64x128 tile, 4x8 micro)
__global__ __launch_bounds__(256) void k_gemm(const float* __restrict__ A, int astride,
                                              const float* __restrict__ h, int bstride, int C,
                                              float* __restrict__ out, int O) {
    __shared__ float Ws[8][64], Hs[8][128];
    const int b = blockIdx.z, o0 = blockIdx.y * 64, n0 = blockIdx.x * 128;
    const int t = threadIdx.x, tx = t & 15, ty = t >> 4;
    float acc[4][8] = {};
    const float* hb = h + (size_t)b * bstride;
    for (int c0 = 0; c0 < C; c0 += 8) {
#pragma unroll
        for (int q = 0; q < 2; ++q) {
            int e = t + q * 256;
            int oo = e >> 3, cc = e & 7;
            Ws[cc][oo] = ((c0 + cc) < C) ? A[(size_t)(o0 + oo) * astride + c0 + cc] : 0.f;
        }
        {
            int cc = t >> 5, nn4 = t & 31;
            float4 v = make_float4(0.f, 0.f, 0.f, 0.f);
            if (c0 + cc < C) v = *(const float4*)&hb[(size_t)(c0 + cc) * NV + n0 + nn4 * 4];
            *(float4*)&Hs[cc][nn4 * 4] = v;
        }
        __syncthreads();
#pragma unroll
        for (int c = 0; c < 8; ++c) {
            float4 wv = *(const float4*)&Ws[c][ty * 4];
            float ar[4] = {wv.x, wv.y, wv.z, wv.w};
            float br[8];
            float4 h0 = *(const float4*)&Hs[c][tx * 4];
            float4 h1 = *(const float4*)&Hs[c][64 + tx * 4];
            br[0] = h0.x; br[1] = h0.y; br[2] = h0.z; br[3] = h0.w;
            br[4] = h1.x; br[5] = h1.y; br[6] = h1.z; br[7] = h1.w;
#pragma unroll
            for (int a = 0; a < 4; ++a)
#pragma unroll
                for (int q = 0; q < 8; ++q) acc[a][q] += ar[a] * br[q];
        }
        __syncthreads();
    }
#pragma unroll
    for (int a = 0; a < 4; ++a) {
        int o = o0 + ty * 4 + a;
        float* outp = out + ((size_t)b * O + o) * NV + n0;
        float4 s0 = make_float4(acc[a][0], acc[a][1], acc[a][2], acc[a][3]);
        float4 s1 = make_float4(acc[a][4], acc[a][5], acc[a][6], acc[a][7]);
        *(float4*)&outp[tx * 4] = s0;
        *(float4*)&outp[64 + tx * 4] = s1;
    }
}

// ---------- h_out[b][o][n] = mean_k lrelu( a*(p[b][o][idx[n][k]] + d[b][o][n]) + c0 )
__global__ __launch_bounds__(256) void k_edge(const float* __restrict__ pd,
                                              const int* __restrict__ idx,
                                              const float* __restrict__ ga, const float* __restrict__ be,
                                              const float* __restrict__ mu, const float* __restrict__ va,
                                              float* __restrict__ out, int out_bstride, int O) {
    const int n = blockIdx.x * 256 + threadIdx.x;
    const int o = blockIdx.y, b = blockIdx.z;
    const float a  = ga[o] / sqrtf(va[o] + 1e-5f);
    const float c0 = be[o] - mu[o] * a;
    const float* pb = pd + ((size_t)b * 2 * O + o) * NV;
    const float dv  = pd[((size_t)b * 2 * O + O + o) * NV + n];
    const int* ip   = idx + ((size_t)b * NV + n) * KNN;
    float s = 0.f;
#pragma unroll
    for (int k = 0; k < KNN; ++k) {
        int j = ip[k];
        float y = fmaf(a, pb[j] + dv, c0);
        s += (y > 0.f) ? y : 0.2f * y;
    }
    out[(size_t)b * out_bstride + (size_t)o * NV + n] = s * (1.f / KNN);
}

// ---------- pooled[b][o] = mean_n hf[b][o][n]
__global__ __launch_bounds__(256) void k_pool(const float* __restrict__ hf, float* __restrict__ pooled) {
    const int o = blockIdx.x, b = blockIdx.y;
    const float* hp = hf + ((size_t)b * 512 + o) * NV;
    float s = 0.f;
    for (int i = threadIdx.x; i < NV; i += 256) s += hp[i];
#pragma unroll
    for (int off = 32; off > 0; off >>= 1) s += __shfl_down(s, off, 64);
    __shared__ float red[4];
    if ((threadIdx.x & 63) == 0) red[threadIdx.x >> 6] = s;
    __syncthreads();
    if (threadIdx.x == 0)
        pooled[(size_t)b * 512 + o] = (red[0] + red[1] + red[2] + red[3]) * (1.f / NV);
}

// ---------- out[b][j] = sum_o pooled[b][o] * We[j][o]
__global__ __launch_bounds__(256) void k_final(const float* __restrict__ pooled, const float* __restrict__ We,
                                               float* __restrict__ out) {
    const int j = threadIdx.x, b = blockIdx.x;
    __shared__ float ps[512];
    for (int o = threadIdx.x; o < 512; o += 256) ps[o] = pooled[b * 512 + o];
    __syncthreads();
    float s = 0.f;
    for (int o = 0; o < 512; ++o) s += ps[o] * We[(size_t)j * 512 + o];
    out[b * 256 + j] = s;
}

extern "C" void kernel_launch(void* const* d_in, const int* in_sizes, int n_in,
                              void* d_out, int out_size, void* d_ws, size_t ws_size,
                              hipStream_t stream) {
    const float* x  = (const float*)d_in[0];
    const float* W0 = (const float*)d_in[1];
    const float* g0 = (const float*)d_in[2];
    const float* b0 = (const float*)d_in[3];
    const float* m0 = (const float*)d_in[4];
    const float* v0 = (const float*)d_in[5];
    const float* W1 = (const float*)d_in[6];
    const float* g1 = (const float*)d_in[7];
    const float* b1 = (const float*)d_in[8];
    const float* m1 = (const float*)d_in[9];
    const float* v1 = (const float*)d_in[10];
    const float* W2 = (const float*)d_in[11];
    const float* g2 = (const float*)d_in[12];
    const float* b2 = (const float*)d_in[13];
    const float* m2 = (const float*)d_in[14];
    const float* v2 = (const float*)d_in[15];
    const float* Wf = (const float*)d_in[16];
    const float* gf = (const float*)d_in[17];
    const float* bf = (const float*)d_in[18];
    const float* mf = (const float*)d_in[19];
    const float* vf = (const float*)d_in[20];
    const float* We = (const float*)d_in[21];

    float* ws = (float*)d_ws;
    float* hx     = ws;                         // 24576
    float* cat    = hx + 24576;                 // 3670016
    float* xx     = cat + 3670016;              // 8192
    int*   idx    = (int*)(xx + 8192);          // 163840 ints
    float* pd     = (float*)(idx + 163840);     // 8388608 (2O max = 1024)
    float* wb     = pd + 8388608;               // 458752
    float* hf     = wb + 458752;                // 4194304
    float* pooled = hf + 4194304;               // 4096

    k_transpose<<<96, 256, 0, stream>>>(x, hx);

    auto run_layer = [&](const float* h, int C, int bstride, const float* W,
                         const float* g, const float* be, const float* m, const float* v,
                         int O, float* outp, int obstride) {
        k_xx<<<32, 256, 0, stream>>>(h, xx, C, bstride);
        k_knn<<<dim3(8, 32), 512, 0, stream>>>(h, xx, C, bstride, idx);
        int pn = 2 * O * C;
        k_pack<<<(pn + 255) / 256, 256, 0, stream>>>(W, wb, C, O);
        k_gemm<<<dim3(8, 2 * O / 64, 8), 256, 0, stream>>>(wb, C, h, bstride, C, pd, 2 * O);
        k_edge<<<dim3(4, O, 8), 256, 0, stream>>>(pd, idx, g, be, m, v, outp, obstride, O);
    };

    run_layer(hx, 3, 3 * NV, W0, g0, b0, m0, v0, 64, cat, 448 * NV);
    run_layer(cat, 64, 448 * NV, W1, g1, b1, m1, v1, 128, cat + 64 * NV, 448 * NV);
    run_layer(cat + 64 * NV, 128, 448 * NV, W2, g2, b2, m2, v2, 256, cat + 192 * NV, 448 * NV);
    run_layer(cat, 448, 448 * NV, Wf, gf, bf, mf, vf, 512, hf, 512 * NV);

    k_pool<<<dim3(512, 8), 256, 0, stream>>>(hf, pooled);
    k_final<<<8, 256, 0, stream>>>(pooled, We, (float*)d_out);
}

// Round 8
// 840.624 us; speedup vs baseline: 1.0034x; 1.0028x over previous
//
#include <hip/hip_runtime.h>
#include <cstdint>

#define KNN 20
#define BV 8
#define NV 1024

// ---- DPP wave64 reduce helpers (rocPRIM pattern): result lands in lane 63.
// ctrl: 0xB1=quad_perm[1,0,3,2](xor1) 0x4E=quad_perm[2,3,0,1](xor2)
//       0x141=row_half_mirror 0x140=row_mirror 0x142=row_bcast15 0x143=row_bcast31
template <int CTRL>
__device__ __forceinline__ unsigned dppmax(unsigned x) {
    unsigned m = (unsigned)__builtin_amdgcn_update_dpp((int)x, (int)x, CTRL, 0xf, 0xf, false);
    return (x > m) ? x : m;
}
template <int CTRL>
__device__ __forceinline__ unsigned dppmin(unsigned x) {
    unsigned m = (unsigned)__builtin_amdgcn_update_dpp((int)x, (int)x, CTRL, 0xf, 0xf, false);
    return (x < m) ? x : m;
}
__device__ __forceinline__ unsigned wave_max_u32(unsigned x) {
    x = dppmax<0xB1>(x); x = dppmax<0x4E>(x); x = dppmax<0x141>(x);
    x = dppmax<0x140>(x); x = dppmax<0x142>(x); x = dppmax<0x143>(x);
    return (unsigned)__builtin_amdgcn_readlane((int)x, 63);
}
__device__ __forceinline__ unsigned wave_min_u32(unsigned x) {
    x = dppmin<0xB1>(x); x = dppmin<0x4E>(x); x = dppmin<0x141>(x);
    x = dppmin<0x140>(x); x = dppmin<0x142>(x); x = dppmin<0x143>(x);
    return (unsigned)__builtin_amdgcn_readlane((int)x, 63);
}

// ---------- transpose x [B,N,3] -> hx [B,3,N]
__global__ __launch_bounds__(256) void k_transpose(const float* __restrict__ x, float* __restrict__ hx) {
    int id = blockIdx.x * 256 + threadIdx.x;
    if (id >= BV * 3 * NV) return;
    int n = id % NV;
    int c = (id / NV) % 3;
    int b = id / (3 * NV);
    hx[id] = x[(b * NV + n) * 3 + c];
}

// ---------- xx[b][n] = sum_c h[b][c][n]^2
__global__ __launch_bounds__(256) void k_xx(const float* __restrict__ h, float* __restrict__ xx,
                                            int C, int bstride) {
    int id = blockIdx.x * 256 + threadIdx.x;
    int n = id % NV, b = id / NV;
    if (b >= BV) return;
    const float* hp = h + (size_t)b * bstride + n;
    float s = 0.f;
    for (int c = 0; c < C; ++c) { float v = hp[(size_t)c * NV]; s += v * v; }
    xx[b * NV + n] = s;
}

// ---------- FUSED kNN: neg-sqdist rows in registers, top-20 in-wave, no D matrix.
// grid (B, N/32); block 512 = 8 waves; wave w owns rows i0+4w..+3; lane owns 16 j's.
__global__ __launch_bounds__(512) void k_knn(const float* __restrict__ h, const float* __restrict__ xx,
                                             int C, int bstride, int* __restrict__ idx) {
    __shared__ float Bs[8][1024];
    const int b = blockIdx.x, i0 = blockIdx.y * 32;
    const int t = threadIdx.x, lane = t & 63, w = t >> 6;
    const int irow = i0 + w * 4;
    float acc[4][16] = {};
    const float* hb = h + (size_t)b * bstride;

    for (int c0 = 0; c0 < C; c0 += 8) {
        __syncthreads();
#pragma unroll
        for (int r = 0; r < 4; ++r) {              // stage Bs[8][1024] = h[c0..c0+7][:]
            int e = r * 512 + t;                   // 2048 float4 groups
            int cc = e >> 8, jj = e & 255;
            float4 v = make_float4(0.f, 0.f, 0.f, 0.f);
            if (c0 + cc < C) v = *(const float4*)&hb[(size_t)(c0 + cc) * NV + jj * 4];
            *(float4*)&Bs[cc][jj * 4] = v;
        }
        __syncthreads();
#pragma unroll
        for (int c = 0; c < 8; ++c) {
            float4 arv = *(const float4*)&Bs[c][irow];     // wave-uniform broadcast
            float ar[4] = {arv.x, arv.y, arv.z, arv.w};
            float br[16];
#pragma unroll
            for (int g = 0; g < 4; ++g) {
                float4 bv = *(const float4*)&Bs[c][g * 256 + (lane << 2)];  // conflict-free b128
                br[g * 4 + 0] = bv.x; br[g * 4 + 1] = bv.y;
                br[g * 4 + 2] = bv.z; br[g * 4 + 3] = bv.w;
            }
#pragma unroll
            for (int a = 0; a < 4; ++a)
#pragma unroll
                for (int q = 0; q < 16; ++q) acc[a][q] += ar[a] * br[q];
        }
    }

    // neg sqdist = 2*dot - xx_i - xx_j
    const float* xb = xx + b * NV;
    float xxj[16];
#pragma unroll
    for (int g = 0; g < 4; ++g) {
        float4 xv = *(const float4*)&xb[g * 256 + (lane << 2)];
        xxj[g * 4 + 0] = xv.x; xxj[g * 4 + 1] = xv.y;
        xxj[g * 4 + 2] = xv.z; xxj[g * 4 + 3] = xv.w;
    }
#pragma unroll
    for (int a = 0; a < 4; ++a) {
        float xi = xb[irow + a];
#pragma unroll
        for (int q = 0; q < 16; ++q) acc[a][q] = 2.f * acc[a][q] - xi - xxj[q];
    }

    // ---- wave-parallel top-20 per row, all-VALU (DPP reduces, no bpermute)
    int* opb = idx + ((size_t)(b * NV + irow)) * KNN;   // rows contiguous: [a*KNN + s]
#pragma unroll 1
    for (int s = 0; s < KNN; ++s) {
#pragma unroll
        for (int a = 0; a < 4; ++a) {
            // local max over 16 regs (static idx; strict > keeps lower q = lower j)
            float bv = acc[a][0]; int bq = 0;
#pragma unroll
            for (int q = 1; q < 16; ++q)
                if (acc[a][q] > bv) { bv = acc[a][q]; bq = q; }
            unsigned u = __float_as_uint(bv);
            unsigned su = ((int)u < 0) ? ~u : (u | 0x80000000u);   // sortable uint
            int myj = ((bq >> 2) << 8) | (lane << 2) | (bq & 3);
            // global value max (wave-uniform), then min-j among value-matching lanes
            unsigned gmax = wave_max_u32(su);
            unsigned cand = (su == gmax) ? (unsigned)myj : 0xFFFFFFFFu;
            int j = (int)wave_min_u32(cand);
            if (lane == 0) opb[a * KNN + s] = j;
            // winner lane poisons its extracted slot (static-index cndmask chain)
            int wq = (((j >> 2) & 63) == lane) ? (((j >> 8) << 2) | (j & 3)) : 99;
#pragma unroll
            for (int q = 0; q < 16; ++q)
                if (wq == q) acc[a][q] = -3.4e38f;
        }
    }
}

// ---------- pack A = [ Wl ; Wr - Wl ]  (2O x C)
__global__ __launch_bounds__(256) void k_pack(const float* __restrict__ W, float* __restrict__ wb,
                                              int C, int O) {
    int id = blockIdx.x * 256 + threadIdx.x;
    if (id >= 2 * O * C) return;
    int c = id % C, o = (id / C) % O, half = id / (C * O);
    float wl = W[(size_t)o * 2 * C + c];
    wb[id] = half ? (W[(size_t)o * 2 * C + C + c] - wl) : wl;
}

// ---------- out[b][o][n] = sum_c A[o][c] * h[b][c][n]   (64x128 tile, 4x8 micro)
__global__ __launch_bounds__(256) void k_gemm(const float* __restrict__ A, int astride,
                                              const float* __restrict__ h, int bstride, int C,
                                              float* __restrict__ out, int O) {
    __shared__ float Ws[8][64], Hs[8][128];
    const int b = blockIdx.z, o0 = blockIdx.y * 64, n0 = blockIdx.x * 128;
    const int t = threadIdx.x, tx = t & 15, ty = t >> 4;
    float acc[4][8] = {};
    const float* hb = h + (size_t)b * bstride;
    for (int c0 = 0; c0 < C; c0 += 8) {
#pragma unroll
        for (int q = 0; q < 2; ++q) {
            int e = t + q * 256;
            int oo = e >> 3, cc = e & 7;
            Ws[cc][oo] = ((c0 + cc) < C) ? A[(size_t)(o0 + oo) * astride + c0 + cc] : 0.f;
        }
        {
            int cc = t >> 5, nn4 = t & 31;
            float4 v = make_float4(0.f, 0.f, 0.f, 0.f);
            if (c0 + cc < C) v = *(const float4*)&hb[(size_t)(c0 + cc) * NV + n0 + nn4 * 4];
            *(float4*)&Hs[cc][nn4 * 4] = v;
        }
        __syncthreads();
#pragma unroll
        for (int c = 0; c < 8; ++c) {
            float4 wv = *(const float4*)&Ws[c][ty * 4];
            float ar[4] = {wv.x, wv.y, wv.z, wv.w};
            float br[8];
            float4 h0 = *(const float4*)&Hs[c][tx * 4];
            float4 h1 = *(const float4*)&Hs[c][64 + tx * 4];
            br[0] = h0.x; br[1] = h0.y; br[2] = h0.z; br[3] = h0.w;
            br[4] = h1.x; br[5] = h1.y; br[6] = h1.z; br[7] = h1.w;
#pragma unroll
            for (int a = 0; a < 4; ++a)
#pragma unroll
                for (int q = 0; q < 8; ++q) acc[a][q] += ar[a] * br[q];
        }
        __syncthreads();
    }
#pragma unroll
    for (int a = 0; a < 4; ++a) {
        int o = o0 + ty * 4 + a;
        float* outp = out + ((size_t)b * O + o) * NV + n0;
        float4 s0 = make_float4(acc[a][0], acc[a][1], acc[a][2], acc[a][3]);
        float4 s1 = make_float4(acc[a][4], acc[a][5], acc[a][6], acc[a][7]);
        *(float4*)&outp[tx * 4] = s0;
        *(float4*)&outp[64 + tx * 4] = s1;
    }
}

// ---------- h_out[b][o][n] = mean_k lrelu( a*(p[b][o][idx[n][k]] + d[b][o][n]) + c0 )
__global__ __launch_bounds__(256) void k_edge(const float* __restrict__ pd,
                                              const int* __restrict__ idx,
                                              const float* __restrict__ ga, const float* __restrict__ be,
                                              const float* __restrict__ mu, const float* __restrict__ va,
                                              float* __restrict__ out, int out_bstride, int O) {
    const int n = blockIdx.x * 256 + threadIdx.x;
    const int o = blockIdx.y, b = blockIdx.z;
    const float a  = ga[o] / sqrtf(va[o] + 1e-5f);
    const float c0 = be[o] - mu[o] * a;
    const float* pb = pd + ((size_t)b * 2 * O + o) * NV;
    const float dv  = pd[((size_t)b * 2 * O + O + o) * NV + n];
    const int* ip   = idx + ((size_t)b * NV + n) * KNN;
    float s = 0.f;
#pragma unroll
    for (int k = 0; k < KNN; ++k) {
        int j = ip[k];
        float y = fmaf(a, pb[j] + dv, c0);
        s += (y > 0.f) ? y : 0.2f * y;
    }
    out[(size_t)b * out_bstride + (size_t)o * NV + n] = s * (1.f / KNN);
}

// ---------- pooled[b][o] = mean_n hf[b][o][n]
__global__ __launch_bounds__(256) void k_pool(const float* __restrict__ hf, float* __restrict__ pooled) {
    const int o = blockIdx.x, b = blockIdx.y;
    const float* hp = hf + ((size_t)b * 512 + o) * NV;
    float s = 0.f;
    for (int i = threadIdx.x; i < NV; i += 256) s += hp[i];
#pragma unroll
    for (int off = 32; off > 0; off >>= 1) s += __shfl_down(s, off, 64);
    __shared__ float red[4];
    if ((threadIdx.x & 63) == 0) red[threadIdx.x >> 6] = s;
    __syncthreads();
    if (threadIdx.x == 0)
        pooled[(size_t)b * 512 + o] = (red[0] + red[1] + red[2] + red[3]) * (1.f / NV);
}

// ---------- out[b][j] = sum_o pooled[b][o] * We[j][o]
__global__ __launch_bounds__(256) void k_final(const float* __restrict__ pooled, const float* __restrict__ We,
                                               float* __restrict__ out) {
    const int j = threadIdx.x, b = blockIdx.x;
    __shared__ float ps[512];
    for (int o = threadIdx.x; o < 512; o += 256) ps[o] = pooled[b * 512 + o];
    __syncthreads();
    float s = 0.f;
    for (int o = 0; o < 512; ++o) s += ps[o] * We[(size_t)j * 512 + o];
    out[b * 256 + j] = s;
}

extern "C" void kernel_launch(void* const* d_in, const int* in_sizes, int n_in,
                              void* d_out, int out_size, void* d_ws, size_t ws_size,
                              hipStream_t stream) {
    const float* x  = (const float*)d_in[0];
    const float* W0 = (const float*)d_in[1];
    const float* g0 = (const float*)d_in[2];
    const float* b0 = (const float*)d_in[3];
    const float* m0 = (const float*)d_in[4];
    const float* v0 = (const float*)d_in[5];
    const float* W1 = (const float*)d_in[6];
    const float* g1 = (const float*)d_in[7];
    const float* b1 = (const float*)d_in[8];
    const float* m1 = (const float*)d_in[9];
    const float* v1 = (const float*)d_in[10];
    const float* W2 = (const float*)d_in[11];
    const float* g2 = (const float*)d_in[12];
    const float* b2 = (const float*)d_in[13];
    const float* m2 = (const float*)d_in[14];
    const float* v2 = (const float*)d_in[15];
    const float* Wf = (const float*)d_in[16];
    const float* gf = (const float*)d_in[17];
    const float* bf = (const float*)d_in[18];
    const float* mf = (const float*)d_in[19];
    const float* vf = (const float*)d_in[20];
    const float* We = (const float*)d_in[21];

    float* ws = (float*)d_ws;
    float* hx     = ws;                         // 24576
    float* cat    = hx + 24576;                 // 3670016
    float* xx     = cat + 3670016;              // 8192
    int*   idx    = (int*)(xx + 8192);          // 163840 ints
    float* pd     = (float*)(idx + 163840);     // 8388608 (2O max = 1024)
    float* wb     = pd + 8388608;               // 458752
    float* hf     = wb + 458752;                // 4194304
    float* pooled = hf + 4194304;               // 4096

    k_transpose<<<96, 256, 0, stream>>>(x, hx);

    auto run_layer = [&](const float* h, int C, int bstride, const float* W,
                         const float* g, const float* be, const float* m, const float* v,
                         int O, float* outp, int obstride) {
        k_xx<<<32, 256, 0, stream>>>(h, xx, C, bstride);
        k_knn<<<dim3(8, 32), 512, 0, stream>>>(h, xx, C, bstride, idx);
        int pn = 2 * O * C;
        k_pack<<<(pn + 255) / 256, 256, 0, stream>>>(W, wb, C, O);
        k_gemm<<<dim3(8, 2 * O / 64, 8), 256, 0, stream>>>(wb, C, h, bstride, C, pd, 2 * O);
        k_edge<<<dim3(4, O, 8), 256, 0, stream>>>(pd, idx, g, be, m, v, outp, obstride, O);
    };

    run_layer(hx, 3, 3 * NV, W0, g0, b0, m0, v0, 64, cat, 448 * NV);
    run_layer(cat, 64, 448 * NV, W1, g1, b1, m1, v1, 128, cat + 64 * NV, 448 * NV);
    run_layer(cat + 64 * NV, 128, 448 * NV, W2, g2, b2, m2, v2, 256, cat + 192 * NV, 448 * NV);
    run_layer(cat, 448, 448 * NV, Wf, gf, bf, mf, vf, 512, hf, 512 * NV);

    k_pool<<<dim3(512, 8), 256, 0, stream>>>(hf, pooled);
    k_final<<<8, 256, 0, stream>>>(pooled, We, (float*)d_out);
}